// Round 4
// baseline (113.804 us; speedup 1.0000x reference)
//
#include <hip/hip_runtime.h>

#define NP   320                // particles
#define HD   32                 // hidden dim
#define MT   4                  // trajectories
#define LS   6                  // snapshots
#define BB   (MT * (LS - 1))    // 20 batch elements
#define NCFG (MT * LS)          // 24 distinct configs
#define SIG2 0.01f
#define L2E2 2.8853900817779268f  // 2*log2(e)

#define NCELL 1024
#define RMAX  12.0f
#define TSCALE ((float)NCELL / RMAX)   // r -> cell
#define CWID   (RMAX / (float)NCELL)   // cell -> r
#define BT    640               // threads per block (2 j-groups of 320)

__device__ __forceinline__ float fexp2(float x){ return __builtin_amdgcn_exp2f(x); }
__device__ __forceinline__ float frcp(float x){ return __builtin_amdgcn_rcpf(x); }
__device__ __forceinline__ float frsq(float x){ return __builtin_amdgcn_rsqf(x); }

// --------------------------------------------------------------------------
// One block per config c = m*LS + l (24 blocks).
//   l in [0,5): drift+laplacian rows (J_diss + J_diff)
//   l == 0    : also energy with coef -1 (telescoped E_curr)
//   l == 5    : energy only, coef +1 (telescoped E_next)
// Per block: build LDS table of (Phi'(r), Phi''(r), phi~(r)) on 1025 cells,
// stage config positions in LDS, then thread t = (group g, row i) accumulates
// over j in its half; groups combine via LDS; group 0 adds closed-form
// one-body V terms and block-reduces to 2 floats in ws.
//
// tanh(z) = 1-2r, r = 1/(exp2(L2E2*z)+1); (1-t^2)=4(r-r^2); t''-terms via u*t.
// --------------------------------------------------------------------------
__global__ __launch_bounds__(BT) void main_kernel(
    const float* __restrict__ data,      // (MT, LS, NP, 2)
    const float* __restrict__ t_snap,    // (LS,)
    const float* __restrict__ V_w1,      // (2, HD)
    const float* __restrict__ V_b1,      // (HD,)
    const float* __restrict__ V_w2,      // (HD,)
    const float* __restrict__ V_b2,      // (1,)
    const float* __restrict__ Phi_w1,    // (HD,)
    const float* __restrict__ Phi_b1,    // (HD,)
    const float* __restrict__ Phi_w2,    // (HD,)
    const float* __restrict__ Phi_b2,    // (1,)
    float* __restrict__ ws)              // [NCFG] S0 parts + [NCFG] S1 parts
{
    __shared__ float4 sTab[NCELL + 2];   // (Phi', Phi'', phi~, 0) per cell
    __shared__ float2 sX[NP];
    __shared__ float4 sCW[HD];           // (w*L2E2, b*L2E2, 4*w*w2, -8*w^2*w2)
    __shared__ float  sPW2[HD];          // Phi_w2
    __shared__ float4 sVW[HD];           // (w0, w1, b, v2)
    __shared__ float  sVS[HD];           // -8*v2*(w0^2+w1^2)
    __shared__ float4 sPart[NP];         // group-1 partials
    __shared__ float  sRed[5][2];

    const int tid  = threadIdx.x;
    const int lane = tid & 63;
    const int wid  = tid >> 6;
    const int cfg  = blockIdx.x;         // = m*LS + l
    const int l    = cfg % LS;
    const bool do_drift = (l < LS - 1);
    const bool do_phi   = (l == 0) || (l == LS - 1);
    const float coef    = (l == LS - 1) ? 1.0f : -1.0f;

    const float2* Xg = (const float2*)(data + (size_t)cfg * NP * 2);

    // ---- stage weights + positions ----
    if (tid < HD) {
        float w  = Phi_w1[tid];
        float bb = Phi_b1[tid];
        float w2 = Phi_w2[tid];
        sCW[tid]  = make_float4(w * L2E2, bb * L2E2, 4.0f * w * w2, -8.0f * w * w * w2);
        sPW2[tid] = w2;
        float w0 = V_w1[tid];
        float w1 = V_w1[HD + tid];
        float v2 = V_w2[tid];
        sVW[tid] = make_float4(w0, w1, V_b1[tid], v2);
        sVS[tid] = -8.0f * v2 * (w0 * w0 + w1 * w1);
    }
    if (tid < NP) sX[tid] = Xg[tid];
    __syncthreads();

    // ---- build the radial table (each block builds its own copy) ----
    for (int c = tid; c < NCELL + 1; c += BT) {
        float rr = (float)c * CWID;
        float f1 = 0.0f, f2 = 0.0f, f3 = 0.0f;
        #pragma unroll
        for (int h = 0; h < HD; ++h) {
            float4 cw = sCW[h];
            float e  = fexp2(fmaf(rr, cw.x, cw.y));
            float rc = frcp(e + 1.0f);
            float u  = fmaf(-rc, rc, rc);        // (1-t^2)/4
            float t  = fmaf(-2.0f, rc, 1.0f);    // tanh
            f1 = fmaf(u,     cw.z, f1);          // Phi'(r)
            f2 = fmaf(u * t, cw.w, f2);          // Phi''(r)
            f3 = fmaf(t, sPW2[h], f3);           // phi~(r)
        }
        sTab[c] = make_float4(f1, f2, f3, 0.0f);
    }
    __syncthreads();

    // ---- pair loop: thread = (group gq, row i), j in group's half ----
    const int gq  = tid / NP;               // 0 or 1
    const int row = tid - gq * NP;
    const float2 xi = sX[row];
    const int j0 = gq * (NP / 2);

    float gx = 0.0f, gy = 0.0f, lp = 0.0f, ph = 0.0f;
    #pragma unroll 4
    for (int jj = 0; jj < NP / 2; ++jj) {
        const int j = j0 + jj;
        const float2 xj = sX[j];
        const float d0 = xi.x - xj.x;
        const float d1 = xi.y - xj.y;
        const float sq = fmaf(d1, d1, d0 * d0);
        const float inv = frsq(sq);             // 1/r (exact-ish), inf/NaN on diag
        const float r   = sq * inv;             // r
        float x = fminf(r * TSCALE, (float)NCELL - 0.001f);
        const int   i0 = (int)x;
        const float fr = x - (float)i0;
        const float4 T0 = sTab[i0];
        const float4 T1 = sTab[i0 + 1];
        const float f1 = fmaf(T1.x - T0.x, fr, T0.x);
        const float f2 = fmaf(T1.y - T0.y, fr, T0.y);
        const float f3 = fmaf(T1.z - T0.z, fr, T0.z);
        const float t0 = f1 * inv;              // Phi'/r
        float cgx = t0 * d0;
        float cgy = t0 * d1;
        float clp = f2 + t0;                    // Phi'' + (d-1)/r*Phi'
        float cph = f3;
        if (j == row) { cgx = 0.0f; cgy = 0.0f; clp = 0.0f; cph = 0.0f; }
        gx += cgx; gy += cgy; lp += clp; ph += cph;
    }

    // ---- combine the two j-groups ----
    if (gq == 1) sPart[row] = make_float4(gx, gy, lp, ph);
    __syncthreads();

    float c0 = 0.0f, c1 = 0.0f;
    if (gq == 0) {
        float4 p = sPart[row];
        gx += p.x; gy += p.y; lp += p.z; ph += p.w;

        // one-body V: grad, laplacian, value (closed form)
        float gvx = 0.0f, gvy = 0.0f, lv = 0.0f, vv = 0.0f;
        #pragma unroll
        for (int h = 0; h < HD; ++h) {
            float4 vw = sVW[h];
            float z  = fmaf(xi.x, vw.x, fmaf(xi.y, vw.y, vw.z));
            float e  = fexp2(z * L2E2);
            float rc = frcp(e + 1.0f);
            float u  = fmaf(-rc, rc, rc);
            float t  = fmaf(-2.0f, rc, 1.0f);
            float cu = 4.0f * u * vw.w;
            gvx = fmaf(cu, vw.x, gvx);
            gvy = fmaf(cu, vw.y, gvy);
            lv  = fmaf(u * t, sVS[h], lv);
            vv  = fmaf(t, vw.w, vv);
        }

        const float invN = 1.0f / (float)NP;
        if (do_drift) {
            float dx = -gvx - gx * invN;
            float dy = -gvy - gy * invN;
            float lap_sum = lv + lp * invN;
            float dt = t_snap[l + 1] - t_snap[l];
            c0 = dt * (dx * dx + dy * dy) * invN + SIG2 * dt * lap_sum * invN;
        }
        if (do_phi) {
            float v = vv + V_b2[0];
            float P = ph + (float)(NP - 1) * Phi_b2[0];
            c1 = coef * (v * invN + P * invN * invN);
        }
    }

    // ---- block reduce (group-0 waves 0..4 hold values; others are zero) ----
    #pragma unroll
    for (int off = 32; off; off >>= 1) {
        c0 += __shfl_down(c0, off, 64);
        c1 += __shfl_down(c1, off, 64);
    }
    if (lane == 0 && wid < 5) { sRed[wid][0] = c0; sRed[wid][1] = c1; }
    __syncthreads();
    if (tid == 0) {
        float S0 = 0.0f, S1 = 0.0f;
        #pragma unroll
        for (int w = 0; w < 5; ++w) { S0 += sRed[w][0]; S1 += sRed[w][1]; }
        ws[cfg]        = S0;
        ws[NCFG + cfg] = S1;
    }
}

// --------------------------------------------------------------------------
// Finalize: sum 24+24 block partials, out = ((S0 - 2*S1)/B)^2
// --------------------------------------------------------------------------
__global__ __launch_bounds__(64) void finalize_kernel(
    const float* __restrict__ ws, float* __restrict__ out)
{
    const int lane = threadIdx.x;
    float a0 = (lane < NCFG) ? ws[lane] : 0.0f;
    float a1 = (lane < NCFG) ? ws[NCFG + lane] : 0.0f;
    #pragma unroll
    for (int off = 32; off; off >>= 1) {
        a0 += __shfl_down(a0, off, 64);
        a1 += __shfl_down(a1, off, 64);
    }
    if (lane == 0) {
        float res = (a0 - 2.0f * a1) / (float)BB;
        out[0] = res * res;
    }
}

extern "C" void kernel_launch(void* const* d_in, const int* in_sizes, int n_in,
                              void* d_out, int out_size, void* d_ws, size_t ws_size,
                              hipStream_t stream) {
    const float* data    = (const float*)d_in[0];
    const float* t_snap  = (const float*)d_in[1];
    const float* V_w1    = (const float*)d_in[2];
    const float* V_b1    = (const float*)d_in[3];
    const float* V_w2    = (const float*)d_in[4];
    const float* V_b2    = (const float*)d_in[5];
    const float* Phi_w1  = (const float*)d_in[6];
    const float* Phi_b1  = (const float*)d_in[7];
    const float* Phi_w2  = (const float*)d_in[8];
    const float* Phi_b2  = (const float*)d_in[9];
    float* ws  = (float*)d_ws;
    float* out = (float*)d_out;

    main_kernel<<<NCFG, BT, 0, stream>>>(
        data, t_snap, V_w1, V_b1, V_w2, V_b2, Phi_w1, Phi_b1, Phi_w2, Phi_b2, ws);

    finalize_kernel<<<1, 64, 0, stream>>>(ws, out);
}

// Round 5
// 91.089 us; speedup vs baseline: 1.2494x; 1.2494x over previous
//
#include <hip/hip_runtime.h>

#define NP   320                // particles
#define HD   32                 // hidden dim
#define MT   4                  // trajectories
#define LS   6                  // snapshots
#define BB   (MT * (LS - 1))    // 20 batch elements
#define NCFG (MT * LS)          // 24 configs
#define ROWS (NCFG * NP)        // 7680 rows
#define SIG2 0.01f
#define L2E2 2.8853900817779268f  // 2*log2(e)

#define NCELL 1024
#define RMAX  12.0f
#define TSCALE ((float)NCELL / RMAX)
#define CWID   (RMAX / (float)NCELL)

// ws layout (floats)
#define OFF_T12 0               // float2[NCELL+1]
#define OFF_T3  2056            // float [NCELL+1]
#define OFF_S0  4096            // float [ROWS]
#define OFF_S1  (4096 + ROWS)   // float [ROWS]

__device__ __forceinline__ float fexp2(float x){ return __builtin_amdgcn_exp2f(x); }
__device__ __forceinline__ float frcp(float x){ return __builtin_amdgcn_rcpf(x); }
__device__ __forceinline__ float frsq(float x){ return __builtin_amdgcn_rsqf(x); }

// --------------------------------------------------------------------------
// Build radial table once: cell c -> r = c*CWID,
//   f1 = Phi'(r), f2 = Phi''(r), f3 = sum_h w2[h]*tanh(r*w+b)
// tanh(z) = 1-2rc, rc = 1/(exp2(L2E2*z)+1); (1-t^2) = 4(rc-rc^2)
// --------------------------------------------------------------------------
__global__ __launch_bounds__(1024) void build_table_kernel(
    const float* __restrict__ Phi_w1, const float* __restrict__ Phi_b1,
    const float* __restrict__ Phi_w2, float* __restrict__ ws)
{
    float2* t12 = (float2*)(ws + OFF_T12);
    float*  t3  = ws + OFF_T3;
    for (int c = threadIdx.x; c < NCELL + 1; c += 1024) {
        float rr = (float)c * CWID;
        float f1 = 0.0f, f2 = 0.0f, f3 = 0.0f;
        #pragma unroll
        for (int h = 0; h < HD; ++h) {
            float w  = Phi_w1[h];
            float bb = Phi_b1[h];
            float w2 = Phi_w2[h];
            float e  = fexp2(fmaf(rr, w, bb) * L2E2);
            float rc = frcp(e + 1.0f);
            float u  = fmaf(-rc, rc, rc);        // (1-t^2)/4
            float t  = fmaf(-2.0f, rc, 1.0f);    // tanh
            f1 = fmaf(u,     4.0f * w * w2,        f1);   // Phi'
            f2 = fmaf(u * t, -8.0f * w * w * w2,   f2);   // Phi''
            f3 = fmaf(t, w2, f3);                          // phi~ (no b2)
        }
        t12[c] = make_float2(f1, f2);
        t3[c]  = f3;
    }
}

// --------------------------------------------------------------------------
// One WAVE per row (cfg, i). 4 rows per block; 320 % 4 == 0 so all rows of a
// block share one config. Stage table + config positions in LDS; lerp per
// pair; in-wave reductions; closed-form one-body V on lanes 0..31.
// Every row writes BOTH partials (0 when not applicable).
// --------------------------------------------------------------------------
__global__ __launch_bounds__(256) void main_kernel(
    const float* __restrict__ data,      // (MT, LS, NP, 2)
    const float* __restrict__ t_snap,    // (LS,)
    const float* __restrict__ V_w1,      // (2, HD)
    const float* __restrict__ V_b1,      // (HD,)
    const float* __restrict__ V_w2,      // (HD,)
    const float* __restrict__ V_b2,      // (1,)
    const float* __restrict__ Phi_b2,    // (1,)
    float* __restrict__ ws)
{
    __shared__ float2 sT12[NCELL + 1];
    __shared__ float  sT3[NCELL + 1];
    __shared__ float2 sX[NP];

    const int tid  = threadIdx.x;
    const int lane = tid & 63;
    const int wid  = tid >> 6;
    const int row0 = blockIdx.x * 4;
    const int cfg  = row0 / NP;          // same for all 4 waves
    const int l    = cfg % LS;

    // ---- stage table + positions ----
    {
        const float2* gT12 = (const float2*)(ws + OFF_T12);
        const float*  gT3  = ws + OFF_T3;
        const float2* Xg   = (const float2*)(data + (size_t)cfg * NP * 2);
        for (int c = tid; c < NCELL + 1; c += 256) {
            sT12[c] = gT12[c];
            sT3[c]  = gT3[c];
        }
        for (int c = tid; c < NP; c += 256) sX[c] = Xg[c];
    }
    __syncthreads();

    const int i = row0 + wid - cfg * NP;
    const float2 xi = sX[i];

    float gx = 0.0f, gy = 0.0f, lp = 0.0f, ph = 0.0f;
    #pragma unroll
    for (int k = 0; k < NP / 64; ++k) {
        const int j = lane + 64 * k;
        const float2 xj = sX[j];
        const float d0 = xi.x - xj.x;
        const float d1 = xi.y - xj.y;
        const float sq = fmaf(d1, d1, d0 * d0);
        const float inv = frsq(sq);              // 1/r; inf on diagonal
        const float r   = sq * inv;
        float x = fminf(r * TSCALE, (float)NCELL - 0.001f);  // NaN-safe clamp
        const int   i0 = (int)x;
        const float fr = x - (float)i0;
        const float2 a = sT12[i0];
        const float2 b = sT12[i0 + 1];
        const float f1 = fmaf(b.x - a.x, fr, a.x);
        const float f2 = fmaf(b.y - a.y, fr, a.y);
        const float f3 = fmaf(sT3[i0 + 1] - sT3[i0], fr, sT3[i0]);
        const float t0 = f1 * inv;               // Phi'/r
        float cgx = t0 * d0;
        float cgy = t0 * d1;
        float clp = f2 + t0;                     // Phi'' + (d-1)/r * Phi'
        float cph = f3;
        if (j == i) { cgx = 0.0f; cgy = 0.0f; clp = 0.0f; cph = 0.0f; }
        gx += cgx; gy += cgy; lp += clp; ph += cph;
    }
    #pragma unroll
    for (int off = 32; off; off >>= 1) {
        gx += __shfl_down(gx, off, 64);
        gy += __shfl_down(gy, off, 64);
        lp += __shfl_down(lp, off, 64);
        ph += __shfl_down(ph, off, 64);
    }

    // ---- one-body V terms, lanes 0..31 (h = lane) ----
    float gvx = 0.0f, gvy = 0.0f, lv = 0.0f, vv = 0.0f;
    if (lane < HD) {
        float w0 = V_w1[lane];
        float w1 = V_w1[HD + lane];
        float z  = fmaf(xi.x, w0, fmaf(xi.y, w1, V_b1[lane]));
        float e  = fexp2(z * L2E2);
        float rc = frcp(e + 1.0f);
        float u  = fmaf(-rc, rc, rc);
        float t  = fmaf(-2.0f, rc, 1.0f);
        float v2 = V_w2[lane];
        float cu = 4.0f * u * v2;
        gvx = cu * w0;
        gvy = cu * w1;
        lv  = -8.0f * u * t * v2 * (w0 * w0 + w1 * w1);
        vv  = t * v2;
        #pragma unroll
        for (int off = 16; off; off >>= 1) {
            gvx += __shfl_xor(gvx, off, 64);
            gvy += __shfl_xor(gvy, off, 64);
            lv  += __shfl_xor(lv,  off, 64);
            vv  += __shfl_xor(vv,  off, 64);
        }
    }

    if (lane == 0) {
        const float invN = 1.0f / (float)NP;
        float c0 = 0.0f, c1 = 0.0f;
        if (l < LS - 1) {
            float dx = -gvx - gx * invN;
            float dy = -gvy - gy * invN;
            float lap_sum = lv + lp * invN;
            float dt = t_snap[l + 1] - t_snap[l];
            c0 = dt * (dx * dx + dy * dy) * invN + SIG2 * dt * lap_sum * invN;
        }
        if (l == 0 || l == LS - 1) {
            const float coef = (l == LS - 1) ? 1.0f : -1.0f;
            float v = vv + V_b2[0];
            float P = ph + (float)(NP - 1) * Phi_b2[0];
            c1 = coef * (v * invN + P * invN * invN);
        }
        const int row = row0 + wid;
        ws[OFF_S0 + row] = c0;
        ws[OFF_S1 + row] = c1;
    }
}

// --------------------------------------------------------------------------
// Reduce: out = ((sum S0 - 2*sum S1)/BB)^2
// --------------------------------------------------------------------------
__global__ __launch_bounds__(1024) void reduce_kernel(
    const float* __restrict__ ws, float* __restrict__ out)
{
    __shared__ float sR[16][2];
    const int tid = threadIdx.x;
    float a0 = 0.0f, a1 = 0.0f;
    for (int idx = tid; idx < ROWS; idx += 1024) {
        a0 += ws[OFF_S0 + idx];
        a1 += ws[OFF_S1 + idx];
    }
    #pragma unroll
    for (int off = 32; off; off >>= 1) {
        a0 += __shfl_down(a0, off, 64);
        a1 += __shfl_down(a1, off, 64);
    }
    const int lane = tid & 63, wid = tid >> 6;
    if (lane == 0) { sR[wid][0] = a0; sR[wid][1] = a1; }
    __syncthreads();
    if (tid == 0) {
        float S0 = 0.0f, S1 = 0.0f;
        #pragma unroll
        for (int w = 0; w < 16; ++w) { S0 += sR[w][0]; S1 += sR[w][1]; }
        float res = (S0 - 2.0f * S1) / (float)BB;
        out[0] = res * res;
    }
}

extern "C" void kernel_launch(void* const* d_in, const int* in_sizes, int n_in,
                              void* d_out, int out_size, void* d_ws, size_t ws_size,
                              hipStream_t stream) {
    const float* data    = (const float*)d_in[0];
    const float* t_snap  = (const float*)d_in[1];
    const float* V_w1    = (const float*)d_in[2];
    const float* V_b1    = (const float*)d_in[3];
    const float* V_w2    = (const float*)d_in[4];
    const float* V_b2    = (const float*)d_in[5];
    const float* Phi_w1  = (const float*)d_in[6];
    const float* Phi_b1  = (const float*)d_in[7];
    const float* Phi_w2  = (const float*)d_in[8];
    const float* Phi_b2  = (const float*)d_in[9];
    float* ws  = (float*)d_ws;
    float* out = (float*)d_out;

    build_table_kernel<<<1, 1024, 0, stream>>>(Phi_w1, Phi_b1, Phi_w2, ws);

    main_kernel<<<ROWS / 4, 256, 0, stream>>>(
        data, t_snap, V_w1, V_b1, V_w2, V_b2, Phi_b2, ws);

    reduce_kernel<<<1, 1024, 0, stream>>>(ws, out);
}